// Round 1
// baseline (201.803 us; speedup 1.0000x reference)
//
#include <hip/hip_runtime.h>
#include <stdint.h>

#define BATCH  4
#define CCH    128
#define GRID_H 128
#define GRID_W 128
#define NNODE  (GRID_H*GRID_W)   // 16384
#define NHEAD  8
#define DH     16

typedef __attribute__((ext_vector_type(8))) short short8;
typedef __attribute__((ext_vector_type(4))) float f32x4;

__device__ inline unsigned short f2bf(float f){
    unsigned u = __float_as_uint(f);
    return (unsigned short)((u + 0x7FFFu + ((u >> 16) & 1u)) >> 16);
}

// ---------------------------------------------------------------------------
// Kernel A: xp[b,n,co] = sum_c x[b,c,n] * W[c,co]   (bf16 MFMA, fp32 acc)
// also a_src[b,n,h] = sum_d xp[b,n,h*16+d]*att_src[h,d], same for a_dst.
// Block: 256 threads (4 waves), 64 nodes. Grid: (N/64, B).
// ---------------------------------------------------------------------------
__global__ __launch_bounds__(256, 2) void kA(
    const float* __restrict__ x, const float* __restrict__ Wl,
    const float* __restrict__ attS, const float* __restrict__ attD,
    float* __restrict__ xp, float* __restrict__ aS, float* __restrict__ aD)
{
    // W packed as bf16 k-pairs: Wp[k2][co] = {W[2k2][co], W[2k2+1][co]}
    // pad 130 dwords/row -> bank=(2*k2+co)%32 -> worst 2-way (free)
    __shared__ unsigned Wp[64][130];
    __shared__ unsigned Xp[64][66];      // Xp[c2][node], same packing
    __shared__ float    aSc[2][64][NHEAD];

    const int t  = threadIdx.x;
    const int b  = blockIdx.y;
    const int n0 = blockIdx.x * 64;

    // stage W (fp32 global -> packed bf16 LDS)
    #pragma unroll 4
    for (int it = 0; it < 32; ++it){
        int flat = it*256 + t;
        int k2 = flat >> 7, co = flat & 127;
        float w0 = Wl[(2*k2)*CCH + co];
        float w1 = Wl[(2*k2+1)*CCH + co];
        Wp[k2][co] = (unsigned)f2bf(w0) | ((unsigned)f2bf(w1) << 16);
    }
    // stage x tile
    const float* xb = x + (size_t)b*CCH*NNODE;
    #pragma unroll 4
    for (int it = 0; it < 16; ++it){
        int flat = it*256 + t;
        int c2 = flat >> 6, nd = flat & 63;
        float v0 = xb[(size_t)(2*c2)*NNODE + n0 + nd];
        float v1 = xb[(size_t)(2*c2+1)*NNODE + n0 + nd];
        Xp[c2][nd] = (unsigned)f2bf(v0) | ((unsigned)f2bf(v1) << 16);
    }
    __syncthreads();

    const int w = t >> 6, lane = t & 63;
    const int col = lane & 15, q = lane >> 4;

    f32x4 acc[8];
    #pragma unroll
    for (int ct = 0; ct < 8; ++ct) acc[ct] = (f32x4)(0.f);

    // A[m=lane&15][k=(lane>>4)*8+j], B[k=(lane>>4)*8+j][n=lane&15]
    #pragma unroll
    for (int kc = 0; kc < 4; ++kc){
        const int k2b = kc*16 + q*4;
        union { unsigned u[4]; short8 s; } fa;
        fa.u[0] = Xp[k2b+0][w*16+col];
        fa.u[1] = Xp[k2b+1][w*16+col];
        fa.u[2] = Xp[k2b+2][w*16+col];
        fa.u[3] = Xp[k2b+3][w*16+col];
        #pragma unroll
        for (int ct = 0; ct < 8; ++ct){
            union { unsigned u[4]; short8 s; } fb;
            fb.u[0] = Wp[k2b+0][ct*16+col];
            fb.u[1] = Wp[k2b+1][ct*16+col];
            fb.u[2] = Wp[k2b+2][ct*16+col];
            fb.u[3] = Wp[k2b+3][ct*16+col];
            acc[ct] = __builtin_amdgcn_mfma_f32_16x16x32_bf16(fa.s, fb.s, acc[ct], 0, 0, 0);
        }
    }

    // att vectors: lane's d = col, head = ct
    float atS[8], atD[8];
    #pragma unroll
    for (int h = 0; h < 8; ++h){ atS[h] = attS[h*DH + col]; atD[h] = attD[h*DH + col]; }

    // epilogue: C/D layout col=lane&15, row=(lane>>4)*4+reg
    float* xpb = xp + (size_t)b*NNODE*CCH;
    #pragma unroll
    for (int r = 0; r < 4; ++r){
        const int nloc = w*16 + q*4 + r;
        const int n = n0 + nloc;
        #pragma unroll
        for (int ct = 0; ct < 8; ++ct){
            float v = acc[ct][r];
            xpb[(size_t)n*CCH + ct*16 + col] = v;
            float ps = v * atS[ct];
            float pd = v * atD[ct];
            #pragma unroll
            for (int off = 1; off < 16; off <<= 1){
                ps += __shfl_xor(ps, off, 64);
                pd += __shfl_xor(pd, off, 64);
            }
            if (col == 0){
                aSc[0][nloc][ct] = ps;
                aSc[1][nloc][ct] = pd;
            }
        }
    }
    __syncthreads();
    {
        float* aSb = aS + ((size_t)b*NNODE + n0)*NHEAD;
        float* aDb = aD + ((size_t)b*NNODE + n0)*NHEAD;
        int f0 = t, f1 = t + 256;   // 512 floats each
        aSb[f0] = aSc[0][f0>>3][f0&7];
        aSb[f1] = aSc[0][f1>>3][f1&7];
        aDb[f0] = aSc[1][f0>>3][f0&7];
        aDb[f1] = aSc[1][f1>>3][f1&7];
    }
}

// ---------------------------------------------------------------------------
// Kernel B: per-node attention softmax + aggregate + bias + ELU + LayerNorm.
// Wave per node, 2 channels/lane. Block: 4 waves x 8 nodes = 32 nodes (one
// row segment). Output staged in LDS and written coalesced in [B,C,N] layout.
// ---------------------------------------------------------------------------
__global__ __launch_bounds__(256, 2) void kB(
    const float* __restrict__ xp, const float* __restrict__ aS,
    const float* __restrict__ aD, const float* __restrict__ bias,
    const float* __restrict__ gamma, const float* __restrict__ beta,
    float* __restrict__ out)
{
    __shared__ float outT[CCH][33];
    const int t = threadIdx.x, w = t >> 6, lane = t & 63;
    const int b  = blockIdx.y;
    const int n0 = blockIdx.x * 32;
    const float* xpb = xp + (size_t)b*NNODE*CCH;
    const float* aSb = aS + (size_t)b*NNODE*NHEAD;
    const float* aDb = aD + (size_t)b*NNODE*NHEAD;
    const int c0 = lane, c1 = lane + 64;
    const int h0 = lane >> 4, h1 = h0 + 4;
    const float bi0 = bias[c0], bi1 = bias[c1];
    const float g0 = gamma[c0], g1 = gamma[c1];
    const float be0 = beta[c0], be1 = beta[c1];

    for (int i = 0; i < 8; ++i){
        const int nl = w*8 + i;
        const int n  = n0 + nl;
        const int rr = n >> 7, cc = n & 127;
        const float ad0 = aDb[n*NHEAD + h0];
        const float ad1 = aDb[n*NHEAD + h1];

        float s0[9], s1[9];
        float m0 = -1e30f, m1 = -1e30f;
        #pragma unroll
        for (int e = 0; e < 9; ++e){
            const int dr = e/3 - 1, dc = e%3 - 1;
            const bool v = ((unsigned)(rr+dr) < GRID_H) && ((unsigned)(cc+dc) < GRID_W);
            const int src = n + dr*GRID_W + dc;
            float x0 = -1e30f, x1 = -1e30f;
            if (v){
                float as0 = aSb[src*NHEAD + h0];
                float as1 = aSb[src*NHEAD + h1];
                x0 = as0 + ad0; x0 = x0 > 0.f ? x0 : 0.2f*x0;
                x1 = as1 + ad1; x1 = x1 > 0.f ? x1 : 0.2f*x1;
            }
            s0[e] = x0; s1[e] = x1;
            m0 = fmaxf(m0, x0); m1 = fmaxf(m1, x1);
        }

        float w0[9], w1[9];
        float den0 = 0.f, den1 = 0.f;
        #pragma unroll
        for (int e = 0; e < 9; ++e){
            float e0 = (s0[e] > -1e29f) ? __expf(s0[e]-m0) : 0.f;
            float e1 = (s1[e] > -1e29f) ? __expf(s1[e]-m1) : 0.f;
            w0[e] = e0; w1[e] = e1;
            den0 += e0; den1 += e1;
        }
        den0 += w0[4]; den1 += w1[4];        // appended self-loop (duplicate score)
        const float i0 = 1.f / den0;
        const float i1 = 1.f / den1;

        float acc0 = 0.f, acc1 = 0.f;
        #pragma unroll
        for (int e = 0; e < 9; ++e){
            if (s0[e] > -1e29f){             // wave-uniform validity
                const int dr = e/3 - 1, dc = e%3 - 1;
                const int src = n + dr*GRID_W + dc;
                const float* xs = xpb + (size_t)src*CCH;
                float f0 = w0[e]*i0, f1 = w1[e]*i1;
                if (e == 4){ f0 *= 2.f; f1 *= 2.f; }   // self counted twice
                acc0 += f0 * xs[c0];
                acc1 += f1 * xs[c1];
            }
        }

        float o0 = acc0 + bi0, o1 = acc1 + bi1;
        o0 = o0 > 0.f ? o0 : __expf(o0) - 1.f;   // ELU
        o1 = o1 > 0.f ? o1 : __expf(o1) - 1.f;

        float sm = o0 + o1, sq = o0*o0 + o1*o1;
        #pragma unroll
        for (int off = 32; off >= 1; off >>= 1){
            sm += __shfl_xor(sm, off, 64);
            sq += __shfl_xor(sq, off, 64);
        }
        const float mu  = sm * (1.f/128.f);
        float var = sq * (1.f/128.f) - mu*mu;
        var = var < 0.f ? 0.f : var;
        const float rstd = rsqrtf(var + 1e-5f);
        outT[c0][nl] = (o0 - mu)*rstd*g0 + be0;
        outT[c1][nl] = (o1 - mu)*rstd*g1 + be1;
    }
    __syncthreads();

    float* ob = out + (size_t)b*CCH*NNODE + n0;
    #pragma unroll
    for (int it = 0; it < 16; ++it){
        int c = it*8 + (t >> 5);
        int coln = t & 31;
        ob[(size_t)c*NNODE + coln] = outT[c][coln];
    }
}

extern "C" void kernel_launch(void* const* d_in, const int* in_sizes, int n_in,
                              void* d_out, int out_size, void* d_ws, size_t ws_size,
                              hipStream_t stream)
{
    const float* x    = (const float*)d_in[0];
    const float* Wl   = (const float*)d_in[1];
    const float* attS = (const float*)d_in[2];
    const float* attD = (const float*)d_in[3];
    const float* bias = (const float*)d_in[4];
    const float* gamma= (const float*)d_in[5];
    const float* beta = (const float*)d_in[6];
    float* out = (float*)d_out;

    float* xp = (float*)d_ws;                                  // B*N*C
    float* aS = xp + (size_t)BATCH*NNODE*CCH;                  // B*N*8
    float* aD = aS + (size_t)BATCH*NNODE*NHEAD;                // B*N*8

    kA<<<dim3(NNODE/64, BATCH), 256, 0, stream>>>(x, Wl, attS, attD, xp, aS, aD);
    kB<<<dim3(NNODE/32, BATCH), 256, 0, stream>>>(xp, aS, aD, bias, gamma, beta, out);
}

// Round 2
// 134.389 us; speedup vs baseline: 1.5016x; 1.5016x over previous
//
#include <hip/hip_runtime.h>
#include <stdint.h>

#define BATCH  4
#define CCH    128
#define GRID_H 128
#define GRID_W 128
#define NNODE  (GRID_H*GRID_W)   // 16384
#define NHEAD  8
#define DH     16
#define XPW    144               // xp row: 128 ch + 8 aS + 8 aD
#define WPAD   68                // padded k2 row (64 + 4)

typedef __attribute__((ext_vector_type(8))) short short8;
typedef __attribute__((ext_vector_type(4))) float f32x4;
typedef __attribute__((ext_vector_type(4))) unsigned u32x4;

__device__ inline unsigned short f2bf(float f){
    unsigned u = __float_as_uint(f);
    return (unsigned short)((u + 0x7FFFu + ((u >> 16) & 1u)) >> 16);
}
__device__ inline unsigned packbf(float a, float b){
    return (unsigned)f2bf(a) | ((unsigned)f2bf(b) << 16);
}

// ---------------------------------------------------------------------------
// kW: pack augmented W' (144 cols: W | W@attS_h | W@attD_h) to bf16 k-pairs,
// co-major: Wb[co*WPAD + k2] = {bf16 W'[2k2][co], bf16 W'[2k2+1][co]}.
// Grid 16 blocks; block b owns k2 in [4b, 4b+4) i.e. c in [8b, 8b+8).
// ---------------------------------------------------------------------------
__global__ void kW(const float* __restrict__ Wl, const float* __restrict__ attS,
                   const float* __restrict__ attD, unsigned* __restrict__ Wb)
{
    __shared__ float Wa[8][16];          // augmented cols for this block's 8 c's
    const int t = threadIdx.x;
    const int cbase = blockIdx.x * 8;    // c range
    if (t < 128){
        int cl = t >> 4, j = t & 15;     // j: 0..7 attS heads, 8..15 attD heads
        const float* av = (j < 8 ? attS + j*DH : attD + (j-8)*DH);
        const float* wr = Wl + (size_t)(cbase + cl)*CCH + (j & 7)*DH;
        float s = 0.f;
        #pragma unroll
        for (int d = 0; d < DH; ++d) s += wr[d]*av[d];
        Wa[cl][j] = s;
    }
    __syncthreads();
    // pack 4 k2 x 144 co = 576 entries
    for (int it = 0; it < 3; ++it){
        int flat = it*256 + t;
        if (flat < 576){
            int k2l = flat / 144, co = flat % 144;
            int k2 = blockIdx.x*4 + k2l;
            float w0, w1;
            if (co < CCH){
                w0 = Wl[(size_t)(2*k2)*CCH + co];
                w1 = Wl[(size_t)(2*k2+1)*CCH + co];
            } else {
                w0 = Wa[2*k2l][co-CCH];
                w1 = Wa[2*k2l+1][co-CCH];
            }
            Wb[co*WPAD + k2] = packbf(w0, w1);
        }
    }
}

// ---------------------------------------------------------------------------
// kA: xp2[b][n][co] = sum_c x[b,c,n]*W'[c,co]  (bf16 MFMA, 64-node tiles)
// Operand LDS layouts are row-major per MFMA row -> all fragment reads are
// ds_read_b128. Grid (N/64, B), 256 threads (4 waves x 16 nodes).
// ---------------------------------------------------------------------------
__global__ __launch_bounds__(256, 2) void kA(
    const float* __restrict__ x, const unsigned* __restrict__ Wbg,
    float* __restrict__ xp2)
{
    __shared__ __align__(16) unsigned WbL[XPW*WPAD];   // 9792 u32
    __shared__ __align__(16) unsigned Xa[64*WPAD];     // 4352 u32

    const int t  = threadIdx.x;
    const int b  = blockIdx.y;
    const int n0 = blockIdx.x * 64;

    // stage W' (flat copy, b128)
    #pragma unroll
    for (int it = 0; it < 10; ++it){
        int flat4 = it*256 + t;
        if (flat4 < (XPW*WPAD)/4){
            u32x4 v = *(const u32x4*)(Wbg + flat4*4);
            *(u32x4*)(&WbL[flat4*4]) = v;
        }
    }
    // stage x tile: lane loads float4 (4 nodes) of 2 adjacent channels, packs
    const float* xb = x + (size_t)b*CCH*NNODE + n0;
    {
        const int g = t & 15;            // node group (4 nodes)
        #pragma unroll
        for (int it = 0; it < 4; ++it){
            int c2 = (t >> 4) + it*16;   // channel pair 0..63
            const float* p0 = xb + (size_t)(2*c2)*NNODE + 4*g;
            f32x4 v0 = *(const f32x4*)p0;
            f32x4 v1 = *(const f32x4*)(p0 + NNODE);
            #pragma unroll
            for (int i = 0; i < 4; ++i)
                Xa[(4*g+i)*WPAD + c2] = packbf(v0[i], v1[i]);
        }
    }
    __syncthreads();

    const int w = t >> 6, lane = t & 63;
    const int col = lane & 15, q = lane >> 4;
    const int row = w*16 + col;          // node within tile (m index)

    f32x4 acc[9];
    #pragma unroll
    for (int ct = 0; ct < 9; ++ct) acc[ct] = (f32x4)(0.f);

    union U { u32x4 u; short8 s; };
    #pragma unroll
    for (int kc = 0; kc < 4; ++kc){
        const int kof = kc*16 + q*4;
        U fa; fa.u = *(const u32x4*)(&Xa[row*WPAD + kof]);
        #pragma unroll
        for (int ct = 0; ct < 9; ++ct){
            U fb; fb.u = *(const u32x4*)(&WbL[(ct*16+col)*WPAD + kof]);
            acc[ct] = __builtin_amdgcn_mfma_f32_16x16x32_bf16(fa.s, fb.s, acc[ct], 0, 0, 0);
        }
    }

    // epilogue: C/D layout col=lane&15, row(node offset)=q*4+r
    float* xr = xp2 + (size_t)b*NNODE*XPW;
    #pragma unroll
    for (int ct = 0; ct < 9; ++ct){
        #pragma unroll
        for (int r = 0; r < 4; ++r){
            const int n = n0 + w*16 + q*4 + r;
            xr[(size_t)n*XPW + ct*16 + col] = acc[ct][r];
        }
    }
}

// ---------------------------------------------------------------------------
// kB: per-node softmax-attention aggregate + bias + ELU + LayerNorm.
// Wave per node (8 nodes/wave), lane owns channels (2l, 2l+1) -> one head per
// lane. All 19 loads per node are unconditional (clamped src) so they batch.
// ---------------------------------------------------------------------------
__global__ __launch_bounds__(256, 4) void kB(
    const float* __restrict__ xp2, const float* __restrict__ bias,
    const float* __restrict__ gamma, const float* __restrict__ beta,
    float* __restrict__ out)
{
    __shared__ float outT[CCH][33];
    const int t = threadIdx.x, w = t >> 6, l = t & 63;
    const int b  = blockIdx.y;
    const int n0 = blockIdx.x * 32;
    const float* xpb = xp2 + (size_t)b*NNODE*XPW;
    const int h = l >> 3;                 // head for both owned channels
    const float2 bi = *(const float2*)(bias  + 2*l);
    const float2 ga = *(const float2*)(gamma + 2*l);
    const float2 be = *(const float2*)(beta  + 2*l);

    for (int i = 0; i < 8; ++i){
        const int nl = w*8 + i;
        const int n  = n0 + nl;
        const int rr = n >> 7, cc = n & 127;

        int srcv[9]; bool val[9];
        #pragma unroll
        for (int e = 0; e < 9; ++e){
            const int dr = e/3 - 1, dc = e%3 - 1;
            const bool v = ((unsigned)(rr+dr) < GRID_H) && ((unsigned)(cc+dc) < GRID_W);
            val[e]  = v;
            srcv[e] = v ? (n + dr*GRID_W + dc) : n;
        }
        // issue all loads up front (independent)
        const float ad = xpb[(size_t)n*XPW + 136 + h];
        float asv[9];
        #pragma unroll
        for (int e = 0; e < 9; ++e) asv[e] = xpb[(size_t)srcv[e]*XPW + 128 + h];
        float2 xv[9];
        #pragma unroll
        for (int e = 0; e < 9; ++e) xv[e] = *(const float2*)(xpb + (size_t)srcv[e]*XPW + 2*l);

        float s[9], m = -1e30f;
        #pragma unroll
        for (int e = 0; e < 9; ++e){
            float sc = asv[e] + ad;
            sc = sc > 0.f ? sc : 0.2f*sc;      // leaky relu
            s[e] = val[e] ? sc : -1e30f;
            m = fmaxf(m, s[e]);
        }
        float wt[9], den = 0.f;
        #pragma unroll
        for (int e = 0; e < 9; ++e){
            float ex = __expf(s[e] - m);
            wt[e] = val[e] ? ex : 0.f;
            den += wt[e];
        }
        den += wt[4];                           // appended self-loop
        const float inv = 1.f / den;

        float a0 = 0.f, a1 = 0.f;
        #pragma unroll
        for (int e = 0; e < 9; ++e){
            float f = wt[e] * inv;
            if (e == 4) f *= 2.f;               // self counted twice
            a0 += f * xv[e].x;
            a1 += f * xv[e].y;
        }

        float o0 = a0 + bi.x, o1 = a1 + bi.y;
        o0 = o0 > 0.f ? o0 : __expf(o0) - 1.f;  // ELU
        o1 = o1 > 0.f ? o1 : __expf(o1) - 1.f;

        float sm = o0 + o1, sq = o0*o0 + o1*o1;
        #pragma unroll
        for (int off = 32; off >= 1; off >>= 1){
            sm += __shfl_xor(sm, off, 64);
            sq += __shfl_xor(sq, off, 64);
        }
        const float mu  = sm * (1.f/128.f);
        float var = sq * (1.f/128.f) - mu*mu;
        var = var < 0.f ? 0.f : var;
        const float rstd = rsqrtf(var + 1e-5f);
        outT[2*l  ][nl] = (o0 - mu)*rstd*ga.x + be.x;
        outT[2*l+1][nl] = (o1 - mu)*rstd*ga.y + be.y;
    }
    __syncthreads();

    float* ob = out + (size_t)b*CCH*NNODE + n0;
    #pragma unroll
    for (int it = 0; it < 16; ++it){
        int c = it*8 + (t >> 5);
        int coln = t & 31;
        ob[(size_t)c*NNODE + coln] = outT[c][coln];
    }
}

extern "C" void kernel_launch(void* const* d_in, const int* in_sizes, int n_in,
                              void* d_out, int out_size, void* d_ws, size_t ws_size,
                              hipStream_t stream)
{
    const float* x    = (const float*)d_in[0];
    const float* Wl   = (const float*)d_in[1];
    const float* attS = (const float*)d_in[2];
    const float* attD = (const float*)d_in[3];
    const float* bias = (const float*)d_in[4];
    const float* gamma= (const float*)d_in[5];
    const float* beta = (const float*)d_in[6];
    float* out = (float*)d_out;

    float*    xp2 = (float*)d_ws;                                   // B*N*144
    unsigned* Wb  = (unsigned*)(xp2 + (size_t)BATCH*NNODE*XPW);     // 144*68 u32

    kW<<<dim3(16), 256, 0, stream>>>(Wl, attS, attD, Wb);
    kA<<<dim3(NNODE/64, BATCH), 256, 0, stream>>>(x, Wb, xp2);
    kB<<<dim3(NNODE/32, BATCH), 256, 0, stream>>>(xp2, bias, gamma, beta, out);
}

// Round 3
// 122.392 us; speedup vs baseline: 1.6488x; 1.0980x over previous
//
#include <hip/hip_runtime.h>
#include <stdint.h>

#define BATCH  4
#define CCH    128
#define GRID_H 128
#define GRID_W 128
#define NNODE  (GRID_H*GRID_W)   // 16384
#define NHEAD  8
#define DH     16
#define WPAD   68                // padded k2 row (64 + 4), keeps b128 align
#define WROWS  144               // 128 ch + 8 aS + 8 aD

typedef __attribute__((ext_vector_type(8))) short short8;
typedef __attribute__((ext_vector_type(4))) float f32x4;
typedef __attribute__((ext_vector_type(4))) unsigned u32x4;

__device__ inline unsigned short f2bf(float f){
    unsigned u = __float_as_uint(f);
    return (unsigned short)((u + 0x7FFFu + ((u >> 16) & 1u)) >> 16);
}
__device__ inline unsigned packbf(float a, float b){
    return (unsigned)f2bf(a) | ((unsigned)f2bf(b) << 16);
}
__device__ inline float bflo(unsigned u){ return __uint_as_float(u << 16); }
__device__ inline float bfhi(unsigned u){ return __uint_as_float(u & 0xFFFF0000u); }

// ---------------------------------------------------------------------------
// kW: pack augmented W' (144 cols: W | W@attS_h | W@attD_h) to bf16 k-pairs,
// co-major: Wb[co*WPAD + k2] = {bf16 W'[2k2][co], bf16 W'[2k2+1][co]}.
// ---------------------------------------------------------------------------
__global__ void kW(const float* __restrict__ Wl, const float* __restrict__ attS,
                   const float* __restrict__ attD, unsigned* __restrict__ Wb)
{
    __shared__ float Wa[8][16];
    const int t = threadIdx.x;
    const int cbase = blockIdx.x * 8;
    if (t < 128){
        int cl = t >> 4, j = t & 15;
        const float* av = (j < 8 ? attS + j*DH : attD + (j-8)*DH);
        const float* wr = Wl + (size_t)(cbase + cl)*CCH + (j & 7)*DH;
        float s = 0.f;
        #pragma unroll
        for (int d = 0; d < DH; ++d) s += wr[d]*av[d];
        Wa[cl][j] = s;
    }
    __syncthreads();
    for (int it = 0; it < 3; ++it){
        int flat = it*256 + t;
        if (flat < 576){
            int k2l = flat / 144, co = flat % 144;
            int k2 = blockIdx.x*4 + k2l;
            float w0, w1;
            if (co < CCH){
                w0 = Wl[(size_t)(2*k2)*CCH + co];
                w1 = Wl[(size_t)(2*k2+1)*CCH + co];
            } else {
                w0 = Wa[2*k2l][co-CCH];
                w1 = Wa[2*k2l+1][co-CCH];
            }
            Wb[co*WPAD + k2] = packbf(w0, w1);
        }
    }
}

// ---------------------------------------------------------------------------
// kA: 128-node tiles. xp (bf16 ushort [B][N][128]) + scores (fp32 [B][N][16],
// interleaved aS/aD per head). 4 waves x 2 m-tiles x 9 ct-tiles.
// ---------------------------------------------------------------------------
__global__ __launch_bounds__(256, 2) void kA(
    const float* __restrict__ x, const unsigned* __restrict__ Wbg,
    unsigned short* __restrict__ xpb, float* __restrict__ scb)
{
    __shared__ __align__(16) unsigned WbL[WROWS*WPAD];   // 39168 B
    __shared__ __align__(16) unsigned Xa[128*WPAD];      // 34816 B

    const int t  = threadIdx.x;
    const int b  = blockIdx.y;
    const int n0 = blockIdx.x * 128;

    #pragma unroll
    for (int it = 0; it < 10; ++it){
        int f4 = it*256 + t;
        if (f4 < (WROWS*WPAD)/4)
            *(u32x4*)(&WbL[f4*4]) = *(const u32x4*)(Wbg + (size_t)f4*4);
    }
    const float* xb = x + (size_t)b*CCH*NNODE + n0;
    {
        const int g = t & 31, c2b = t >> 5;        // g: 4-node group (coalesced)
        #pragma unroll
        for (int it = 0; it < 8; ++it){
            int c2 = c2b + it*8;
            const float* p0 = xb + (size_t)(2*c2)*NNODE + 4*g;
            f32x4 v0 = *(const f32x4*)p0;
            f32x4 v1 = *(const f32x4*)(p0 + NNODE);
            #pragma unroll
            for (int i = 0; i < 4; ++i)
                Xa[(4*g+i)*WPAD + c2] = packbf(v0[i], v1[i]);
        }
    }
    __syncthreads();

    const int w = t >> 6, lane = t & 63;
    const int col = lane & 15, q = lane >> 4;

    f32x4 acc[2][9];
    #pragma unroll
    for (int mi = 0; mi < 2; ++mi)
        #pragma unroll
        for (int ct = 0; ct < 9; ++ct) acc[mi][ct] = (f32x4)(0.f);

    union U { u32x4 u; short8 s; };
    #pragma unroll
    for (int kc = 0; kc < 4; ++kc){
        const int kof = kc*16 + q*4;
        U fa0, fa1;
        fa0.u = *(const u32x4*)(&Xa[((2*w+0)*16+col)*WPAD + kof]);
        fa1.u = *(const u32x4*)(&Xa[((2*w+1)*16+col)*WPAD + kof]);
        #pragma unroll
        for (int ct = 0; ct < 9; ++ct){
            U fb; fb.u = *(const u32x4*)(&WbL[(ct*16+col)*WPAD + kof]);
            acc[0][ct] = __builtin_amdgcn_mfma_f32_16x16x32_bf16(fa0.s, fb.s, acc[0][ct], 0, 0, 0);
            acc[1][ct] = __builtin_amdgcn_mfma_f32_16x16x32_bf16(fa1.s, fb.s, acc[1][ct], 0, 0, 0);
        }
    }

    unsigned short* xr = xpb + (size_t)b*NNODE*CCH;
    float*          sr = scb + (size_t)b*NNODE*16;
    const int sidx = (col < 8) ? 2*col : 2*(col-8)+1;
    #pragma unroll
    for (int mi = 0; mi < 2; ++mi){
        #pragma unroll
        for (int r = 0; r < 4; ++r){
            const int n = n0 + (2*w+mi)*16 + q*4 + r;
            #pragma unroll
            for (int ct = 0; ct < 8; ++ct)
                xr[(size_t)n*CCH + ct*16 + col] = f2bf(acc[mi][ct][r]);
            sr[(size_t)n*16 + sidx] = acc[mi][8][r];
        }
    }
}

// ---------------------------------------------------------------------------
// kB: 64 nodes/block; wave handles 16 nodes as 8 pairs (half-wave per node,
// 4 channels/lane). Per edge: one contiguous 512B bf16 row-pair read + one
// float2 score read. LN via 5-step butterfly within half-waves.
// ---------------------------------------------------------------------------
__global__ __launch_bounds__(256, 4) void kB(
    const unsigned short* __restrict__ xpb, const float* __restrict__ scb,
    const float* __restrict__ bias, const float* __restrict__ gamma,
    const float* __restrict__ beta, float* __restrict__ out)
{
    __shared__ float outT[CCH][65];
    const int t = threadIdx.x, w = t >> 6, lane = t & 63;
    const int h2 = lane >> 5, l2 = lane & 31;
    const int b  = blockIdx.y;
    const int n0 = blockIdx.x * 64;
    const uint2*  xvb = (const uint2*)(xpb + (size_t)b*NNODE*CCH);  // idx: src*32+l2
    const float2* scB = (const float2*)(scb + (size_t)b*NNODE*16);  // idx: src*8+h
    const int h = l2 >> 2;
    const f32x4 bi = *(const f32x4*)(bias  + 4*l2);
    const f32x4 ga = *(const f32x4*)(gamma + 4*l2);
    const f32x4 be = *(const f32x4*)(beta  + 4*l2);

    for (int i = 0; i < 8; ++i){
        const int nl = w*16 + 2*i + h2;
        const int n  = n0 + nl;
        const int rr = n >> 7, cc = n & 127;
        const bool vU = rr > 0, vD = rr < GRID_H-1, vL = cc > 0, vR = cc < GRID_W-1;

        bool val[9]; int src[9];
        #pragma unroll
        for (int e = 0; e < 9; ++e){
            const int dr = e/3 - 1, dc = e%3 - 1;
            const bool vr_ = (dr < 0) ? vU : (dr > 0 ? vD : true);
            const bool vc_ = (dc < 0) ? vL : (dc > 0 ? vR : true);
            val[e] = vr_ && vc_;
            src[e] = val[e] ? (n + dr*GRID_W + dc) : n;
        }
        float2 sc[9];
        #pragma unroll
        for (int e = 0; e < 9; ++e) sc[e] = scB[src[e]*8 + h];
        uint2 xv[9];
        #pragma unroll
        for (int e = 0; e < 9; ++e) xv[e] = xvb[(size_t)src[e]*32 + l2];

        const float ad = sc[4].y;
        float s[9], m = -1e30f;
        #pragma unroll
        for (int e = 0; e < 9; ++e){
            float sv = sc[e].x + ad;
            sv = fmaxf(sv, 0.2f*sv);           // leaky relu
            s[e] = val[e] ? sv : -1e30f;
            m = fmaxf(m, s[e]);
        }
        float wt[9], den = 0.f;
        #pragma unroll
        for (int e = 0; e < 9; ++e){
            float ex = __expf(s[e] - m);
            ex = val[e] ? ex : 0.f;
            wt[e] = ex; den += ex;
        }
        den += wt[4];                           // appended self-loop
        const float inv = __builtin_amdgcn_rcpf(den);

        float a0 = 0.f, a1 = 0.f, a2 = 0.f, a3 = 0.f;
        #pragma unroll
        for (int e = 0; e < 9; ++e){
            float f = wt[e] * inv;
            if (e == 4) f += f;                 // self counted twice
            a0 += f * bflo(xv[e].x);
            a1 += f * bfhi(xv[e].x);
            a2 += f * bflo(xv[e].y);
            a3 += f * bfhi(xv[e].y);
        }

        float o0 = a0 + bi[0], o1 = a1 + bi[1], o2 = a2 + bi[2], o3 = a3 + bi[3];
        o0 = o0 > 0.f ? o0 : __expf(o0) - 1.f;
        o1 = o1 > 0.f ? o1 : __expf(o1) - 1.f;
        o2 = o2 > 0.f ? o2 : __expf(o2) - 1.f;
        o3 = o3 > 0.f ? o3 : __expf(o3) - 1.f;

        float sm = (o0 + o1) + (o2 + o3);
        float sq = o0*o0 + o1*o1 + o2*o2 + o3*o3;
        #pragma unroll
        for (int off = 1; off <= 16; off <<= 1){
            sm += __shfl_xor(sm, off, 64);
            sq += __shfl_xor(sq, off, 64);
        }
        const float mu  = sm * (1.f/128.f);
        float var = sq * (1.f/128.f) - mu*mu;
        var = var < 0.f ? 0.f : var;
        const float rstd = __builtin_amdgcn_rsqf(var + 1e-5f);
        outT[4*l2+0][nl] = (o0 - mu)*rstd*ga[0] + be[0];
        outT[4*l2+1][nl] = (o1 - mu)*rstd*ga[1] + be[1];
        outT[4*l2+2][nl] = (o2 - mu)*rstd*ga[2] + be[2];
        outT[4*l2+3][nl] = (o3 - mu)*rstd*ga[3] + be[3];
    }
    __syncthreads();

    float* ob = out + (size_t)b*CCH*NNODE + n0;
    #pragma unroll
    for (int it = 0; it < 32; ++it){
        int c = it*4 + w;
        ob[(size_t)c*NNODE + lane] = outT[c][lane];
    }
}

extern "C" void kernel_launch(void* const* d_in, const int* in_sizes, int n_in,
                              void* d_out, int out_size, void* d_ws, size_t ws_size,
                              hipStream_t stream)
{
    const float* x    = (const float*)d_in[0];
    const float* Wl   = (const float*)d_in[1];
    const float* attS = (const float*)d_in[2];
    const float* attD = (const float*)d_in[3];
    const float* bias = (const float*)d_in[4];
    const float* gamma= (const float*)d_in[5];
    const float* beta = (const float*)d_in[6];
    float* out = (float*)d_out;

    unsigned short* xpb = (unsigned short*)d_ws;                    // B*N*128 bf16
    float*          scb = (float*)(xpb + (size_t)BATCH*NNODE*CCH);  // B*N*16 f32
    unsigned*       Wb  = (unsigned*)(scb + (size_t)BATCH*NNODE*16);// 144*68 u32

    kW<<<dim3(16), 256, 0, stream>>>(Wl, attS, attD, Wb);
    kA<<<dim3(NNODE/128, BATCH), 256, 0, stream>>>(x, Wb, xpb, scb);
    kB<<<dim3(NNODE/64, BATCH), 256, 0, stream>>>(xpb, scb, bias, gamma, beta, out);
}

// Round 4
// 118.038 us; speedup vs baseline: 1.7096x; 1.0369x over previous
//
#include <hip/hip_runtime.h>
#include <stdint.h>

#define BATCH  4
#define CCH    128
#define GRID_H 128
#define GRID_W 128
#define NNODE  (GRID_H*GRID_W)   // 16384
#define NHEAD  8
#define DH     16
#define WPAD   68                // padded k2 row (64 + 4), keeps b128 align
#define WROWS  144               // 128 ch + 8 aS + 8 aD

typedef __attribute__((ext_vector_type(8))) short short8;
typedef __attribute__((ext_vector_type(4))) float f32x4;
typedef __attribute__((ext_vector_type(4))) unsigned u32x4;

__device__ inline unsigned short f2bf(float f){
    unsigned u = __float_as_uint(f);
    return (unsigned short)((u + 0x7FFFu + ((u >> 16) & 1u)) >> 16);
}
__device__ inline unsigned packbf(float a, float b){
    return (unsigned)f2bf(a) | ((unsigned)f2bf(b) << 16);
}
__device__ inline float bflo(unsigned u){ return __uint_as_float(u << 16); }
__device__ inline float bfhi(unsigned u){ return __uint_as_float(u & 0xFFFF0000u); }

// ---------------------------------------------------------------------------
// kW: pack augmented W' (144 cols: W | W@attS_h | W@attD_h) to bf16 k-pairs,
// co-major: Wb[co*WPAD + k2] = {bf16 W'[2k2][co], bf16 W'[2k2+1][co]}.
// ---------------------------------------------------------------------------
__global__ void kW(const float* __restrict__ Wl, const float* __restrict__ attS,
                   const float* __restrict__ attD, unsigned* __restrict__ Wb)
{
    __shared__ float Wa[8][16];
    const int t = threadIdx.x;
    const int cbase = blockIdx.x * 8;
    if (t < 128){
        int cl = t >> 4, j = t & 15;
        const float* av = (j < 8 ? attS + j*DH : attD + (j-8)*DH);
        const float* wr = Wl + (size_t)(cbase + cl)*CCH + (j & 7)*DH;
        float s = 0.f;
        #pragma unroll
        for (int d = 0; d < DH; ++d) s += wr[d]*av[d];
        Wa[cl][j] = s;
    }
    __syncthreads();
    for (int it = 0; it < 3; ++it){
        int flat = it*256 + t;
        if (flat < 576){
            int k2l = flat / 144, co = flat % 144;
            int k2 = blockIdx.x*4 + k2l;
            float w0, w1;
            if (co < CCH){
                w0 = Wl[(size_t)(2*k2)*CCH + co];
                w1 = Wl[(size_t)(2*k2+1)*CCH + co];
            } else {
                w0 = Wa[2*k2l][co-CCH];
                w1 = Wa[2*k2l+1][co-CCH];
            }
            Wb[co*WPAD + k2] = packbf(w0, w1);
        }
    }
}

// ---------------------------------------------------------------------------
// kA: 128-node tiles, NO x-staging in LDS. A-fragments built directly from
// global (lane (col,q) reads 8 dwords x[c][n]; 16 consecutive cols = full
// 64B segments, each line read once per block). Double-buffered over kc.
// LDS holds only W' (39 KB). xp out as bf16, scores fp32.
// ---------------------------------------------------------------------------
__global__ __launch_bounds__(256, 3) void kA(
    const float* __restrict__ x, const unsigned* __restrict__ Wbg,
    unsigned short* __restrict__ xpb, float* __restrict__ scb)
{
    __shared__ __align__(16) unsigned WbL[WROWS*WPAD];   // 39168 B

    const int t  = threadIdx.x;
    const int b  = blockIdx.y;
    const int n0 = blockIdx.x * 128;

    #pragma unroll
    for (int it = 0; it < 10; ++it){
        int f4 = it*256 + t;
        if (f4 < (WROWS*WPAD)/4)
            *(u32x4*)(&WbL[f4*4]) = *(const u32x4*)(Wbg + (size_t)f4*4);
    }
    __syncthreads();

    const int w = t >> 6, lane = t & 63;
    const int col = lane & 15, q = lane >> 4;
    const float* xb = x + (size_t)b*CCH*NNODE;
    const int nA = n0 + (2*w+0)*16 + col;      // m-tile 0 node of this lane
    const int nB = n0 + (2*w+1)*16 + col;      // m-tile 1 node

    f32x4 acc[2][9];
    #pragma unroll
    for (int mi = 0; mi < 2; ++mi)
        #pragma unroll
        for (int ct = 0; ct < 9; ++ct) acc[mi][ct] = (f32x4)(0.f);

    float xrA[8], xrB[8], x2A[8], x2B[8];
    #pragma unroll
    for (int j = 0; j < 8; ++j){
        const size_t co = (size_t)(q*8 + j)*NNODE;
        xrA[j] = xb[co + nA];
        xrB[j] = xb[co + nB];
    }

    union U { u32x4 u; short8 s; };
    #pragma unroll
    for (int kc = 0; kc < 4; ++kc){
        if (kc < 3){
            #pragma unroll
            for (int j = 0; j < 8; ++j){
                const size_t co = (size_t)((kc+1)*32 + q*8 + j)*NNODE;
                x2A[j] = xb[co + nA];
                x2B[j] = xb[co + nB];
            }
        }
        U fa0, fa1;
        #pragma unroll
        for (int i = 0; i < 4; ++i){
            fa0.u[i] = packbf(xrA[2*i], xrA[2*i+1]);
            fa1.u[i] = packbf(xrB[2*i], xrB[2*i+1]);
        }
        const int kof = kc*16 + q*4;
        #pragma unroll
        for (int ct = 0; ct < 9; ++ct){
            U fb; fb.u = *(const u32x4*)(&WbL[(ct*16+col)*WPAD + kof]);
            acc[0][ct] = __builtin_amdgcn_mfma_f32_16x16x32_bf16(fa0.s, fb.s, acc[0][ct], 0, 0, 0);
            acc[1][ct] = __builtin_amdgcn_mfma_f32_16x16x32_bf16(fa1.s, fb.s, acc[1][ct], 0, 0, 0);
        }
        #pragma unroll
        for (int j = 0; j < 8; ++j){ xrA[j] = x2A[j]; xrB[j] = x2B[j]; }
    }

    unsigned short* xr = xpb + (size_t)b*NNODE*CCH;
    float*          sr = scb + (size_t)b*NNODE*16;
    const int sidx = (col < 8) ? 2*col : 2*(col-8)+1;
    #pragma unroll
    for (int mi = 0; mi < 2; ++mi){
        #pragma unroll
        for (int r = 0; r < 4; ++r){
            const int n = n0 + (2*w+mi)*16 + q*4 + r;
            #pragma unroll
            for (int ct = 0; ct < 8; ++ct)
                xr[(size_t)n*CCH + ct*16 + col] = f2bf(acc[mi][ct][r]);
            sr[(size_t)n*16 + sidx] = acc[mi][8][r];
        }
    }
}

// ---------------------------------------------------------------------------
// kB: 64 nodes/block; half-wave per node, 4 channels/lane, 2-deep software
// pipeline (iter i+1's 18 loads issue before iter i's compute).
// ---------------------------------------------------------------------------
__device__ inline void kb_issue(int n, const float2* __restrict__ scB,
                                const uint2* __restrict__ xvb, int h, int l2,
                                int* vm, float2 sc[9], uint2 xv[9])
{
    const int rr = n >> 7, cc = n & 127;
    const bool vU = rr > 0, vD = rr < GRID_H-1, vL = cc > 0, vR = cc < GRID_W-1;
    int m = 0;
    #pragma unroll
    for (int e = 0; e < 9; ++e){
        const int dr = e/3 - 1, dc = e%3 - 1;
        const bool vr_ = (dr < 0) ? vU : (dr > 0 ? vD : true);
        const bool vc_ = (dc < 0) ? vL : (dc > 0 ? vR : true);
        const bool v = vr_ && vc_;
        const int src = v ? (n + dr*GRID_W + dc) : n;
        m |= ((int)v) << e;
        sc[e] = scB[src*8 + h];
        xv[e] = xvb[(size_t)src*32 + l2];
    }
    *vm = m;
}

__global__ __launch_bounds__(256, 3) void kB(
    const unsigned short* __restrict__ xpb, const float* __restrict__ scb,
    const float* __restrict__ bias, const float* __restrict__ gamma,
    const float* __restrict__ beta, float* __restrict__ out)
{
    __shared__ float outT[CCH][65];
    const int t = threadIdx.x, w = t >> 6, lane = t & 63;
    const int h2 = lane >> 5, l2 = lane & 31;
    const int b  = blockIdx.y;
    const int n0 = blockIdx.x * 64;
    const uint2*  xvb = (const uint2*)(xpb + (size_t)b*NNODE*CCH);
    const float2* scB = (const float2*)(scb + (size_t)b*NNODE*16);
    const int h = l2 >> 2;
    const f32x4 bi = *(const f32x4*)(bias  + 4*l2);
    const f32x4 ga = *(const f32x4*)(gamma + 4*l2);
    const f32x4 be = *(const f32x4*)(beta  + 4*l2);

    float2 scP[2][9]; uint2 xvP[2][9]; int vmP[2];

    #define NODE(i) (n0 + w*16 + 2*(i) + h2)
    kb_issue(NODE(0), scB, xvb, h, l2, &vmP[0], scP[0], xvP[0]);

    #pragma unroll
    for (int ii = 0; ii < 4; ++ii){
        #pragma unroll
        for (int ph = 0; ph < 2; ++ph){
            const int i = 2*ii + ph;
            const int cur = i & 1;
            if (i + 1 < 8)
                kb_issue(NODE(i+1), scB, xvb, h, l2, &vmP[cur^1], scP[cur^1], xvP[cur^1]);

            const int vm = vmP[cur];
            const float2* sc = scP[cur];
            const uint2*  xv = xvP[cur];
            const int nl = w*16 + 2*i + h2;

            const float ad = sc[4].y;
            float s[9], mx = -1e30f;
            #pragma unroll
            for (int e = 0; e < 9; ++e){
                float sv = sc[e].x + ad;
                sv = fmaxf(sv, 0.2f*sv);
                s[e] = ((vm >> e) & 1) ? sv : -1e30f;
                mx = fmaxf(mx, s[e]);
            }
            float wt[9], den = 0.f;
            #pragma unroll
            for (int e = 0; e < 9; ++e){
                float ex = __expf(s[e] - mx);
                ex = ((vm >> e) & 1) ? ex : 0.f;
                wt[e] = ex; den += ex;
            }
            den += wt[4];
            const float inv = __builtin_amdgcn_rcpf(den);

            float a0 = 0.f, a1 = 0.f, a2 = 0.f, a3 = 0.f;
            #pragma unroll
            for (int e = 0; e < 9; ++e){
                float f = wt[e] * inv;
                if (e == 4) f += f;
                a0 += f * bflo(xv[e].x);
                a1 += f * bfhi(xv[e].x);
                a2 += f * bflo(xv[e].y);
                a3 += f * bfhi(xv[e].y);
            }

            float o0 = a0 + bi[0], o1 = a1 + bi[1], o2 = a2 + bi[2], o3 = a3 + bi[3];
            o0 = o0 > 0.f ? o0 : __expf(o0) - 1.f;
            o1 = o1 > 0.f ? o1 : __expf(o1) - 1.f;
            o2 = o2 > 0.f ? o2 : __expf(o2) - 1.f;
            o3 = o3 > 0.f ? o3 : __expf(o3) - 1.f;

            float sm = (o0 + o1) + (o2 + o3);
            float sq = o0*o0 + o1*o1 + o2*o2 + o3*o3;
            #pragma unroll
            for (int off = 1; off <= 16; off <<= 1){
                sm += __shfl_xor(sm, off, 64);
                sq += __shfl_xor(sq, off, 64);
            }
            const float mu  = sm * (1.f/128.f);
            float var = sq * (1.f/128.f) - mu*mu;
            var = var < 0.f ? 0.f : var;
            const float rstd = __builtin_amdgcn_rsqf(var + 1e-5f);
            outT[4*l2+0][nl] = (o0 - mu)*rstd*ga[0] + be[0];
            outT[4*l2+1][nl] = (o1 - mu)*rstd*ga[1] + be[1];
            outT[4*l2+2][nl] = (o2 - mu)*rstd*ga[2] + be[2];
            outT[4*l2+3][nl] = (o3 - mu)*rstd*ga[3] + be[3];
        }
    }
    #undef NODE
    __syncthreads();

    float* ob = out + (size_t)b*CCH*NNODE + n0;
    #pragma unroll
    for (int it = 0; it < 32; ++it){
        int c = it*4 + w;
        ob[(size_t)c*NNODE + lane] = outT[c][lane];
    }
}

extern "C" void kernel_launch(void* const* d_in, const int* in_sizes, int n_in,
                              void* d_out, int out_size, void* d_ws, size_t ws_size,
                              hipStream_t stream)
{
    const float* x    = (const float*)d_in[0];
    const float* Wl   = (const float*)d_in[1];
    const float* attS = (const float*)d_in[2];
    const float* attD = (const float*)d_in[3];
    const float* bias = (const float*)d_in[4];
    const float* gamma= (const float*)d_in[5];
    const float* beta = (const float*)d_in[6];
    float* out = (float*)d_out;

    unsigned short* xpb = (unsigned short*)d_ws;                    // B*N*128 bf16
    float*          scb = (float*)(xpb + (size_t)BATCH*NNODE*CCH);  // B*N*16 f32
    unsigned*       Wb  = (unsigned*)(scb + (size_t)BATCH*NNODE*16);// 144*68 u32

    kW<<<dim3(16), 256, 0, stream>>>(Wl, attS, attD, Wb);
    kA<<<dim3(NNODE/128, BATCH), 256, 0, stream>>>(x, Wb, xpb, scb);
    kB<<<dim3(NNODE/64, BATCH), 256, 0, stream>>>(xpb, scb, bias, gamma, beta, out);
}